// Round 7
// baseline (194.500 us; speedup 1.0000x reference)
//
#include <hip/hip_runtime.h>

#define EPS 1e-5f

typedef __attribute__((ext_vector_type(8))) short short8;
typedef __attribute__((ext_vector_type(4))) float float4v;

__device__ inline unsigned short f2bf(float f) {
  unsigned u = __float_as_uint(f);
  unsigned r = (u + 0x7fffu + ((u >> 16) & 1u)) >> 16;
  return (unsigned short)r;
}
__device__ inline uint pk2(float a, float b) {
  return (uint)f2bf(a) | ((uint)f2bf(b) << 16);
}

// ---------------------------------------------------------------------------
// xform: fold BN into weights + biases (bias block merged as blockIdx 52).
//  - Awt bf16 [kc(18)][mt(8)][q(4)][ml(16)][j(8)] (A-fragment-ready, e pad 128)
//  - Wc fp32 [ci(64)][co(64)] transposed compress weights * inv[co].
// ---------------------------------------------------------------------------
__global__ __launch_bounds__(256) void xform_kernel(
    const float* __restrict__ enc_w, const float* __restrict__ enc_gamma,
    const float* __restrict__ enc_var, const float* __restrict__ comp_w,
    const float* __restrict__ comp_gamma, const float* __restrict__ comp_var,
    const float* __restrict__ enc_b, const float* __restrict__ enc_beta,
    const float* __restrict__ enc_mean, const float* __restrict__ comp_beta,
    const float* __restrict__ comp_mean,
    ushort* __restrict__ Awt, float* __restrict__ Wc,
    float* __restrict__ bias2, float* __restrict__ bias_c) {
  if (blockIdx.x == 52) {
    int t = threadIdx.x;
    if (t < 128) {
      float v = 0.f;
      if (t < 100) {
        float inv = enc_gamma[t] * rsqrtf(enc_var[t] + EPS);
        v = enc_b[t] * inv + enc_beta[t] - enc_mean[t] * inv;
      }
      bias2[t] = v;
    } else if (t < 192) {
      int c = t - 128;
      float inv = comp_gamma[c] * rsqrtf(comp_var[c] + EPS);
      bias_c[c] = comp_beta[c] - comp_mean[c] * inv;
    }
    return;
  }
  int u = blockIdx.x * 256 + threadIdx.x;
  if (u < 9216) {
    int kc = u >> 9, rem = u & 511;
    int mt = rem >> 6, q = (rem >> 4) & 3, ml = rem & 15;
    int e = mt * 16 + ml;
    int t = kc >> 1, h = kc & 1;
    int dy = t / 3, dx = t - dy * 3;
    float inv = (e < 100) ? enc_gamma[e] * rsqrtf(enc_var[e] + EPS) : 0.f;
    ushort o[8];
#pragma unroll
    for (int j = 0; j < 8; ++j) {
      int ci = h * 32 + q * 8 + j;
      float w = (e < 100) ? enc_w[(e * 64 + ci) * 9 + dy * 3 + dx] * inv : 0.f;
      o[j] = f2bf(w);
    }
    uint4 v;
    v.x = (uint)o[0] | ((uint)o[1] << 16);
    v.y = (uint)o[2] | ((uint)o[3] << 16);
    v.z = (uint)o[4] | ((uint)o[5] << 16);
    v.w = (uint)o[6] | ((uint)o[7] << 16);
    *reinterpret_cast<uint4*>(Awt + (size_t)u * 8) = v;
  } else if (u < 9216 + 4096) {
    int v = u - 9216;
    int co = v & 63;
    float inv = comp_gamma[co] * rsqrtf(comp_var[co] + EPS);
    Wc[v] = comp_w[co * 64 + (v >> 6)] * inv;
  }
}

// ---------------------------------------------------------------------------
// compress: 1x1 conv 64->64 + BN + ReLU -> Wm1t bf16 pixel-major, plus Xb
// bf16 pixel-major. Block = 64 px, 1024 blocks. LDS-transposed, coalesced
// in & out; weights via wave-uniform s_loads.
// ---------------------------------------------------------------------------
__global__ __launch_bounds__(256) void compress_kernel(
    const float* __restrict__ X, const float* __restrict__ Wc,
    const float* __restrict__ bias_c, ushort* __restrict__ out,
    ushort* __restrict__ Xb) {
  __shared__ __align__(16) float xtile[64 * 65];
  __shared__ __align__(16) float osm[64 * 68];
  const int tid = threadIdx.x;
  const int p0 = blockIdx.x * 64;
  const int b = p0 >> 14;
  const float* xbase = X + ((size_t)b << 20) + (p0 & 16383);

#pragma unroll
  for (int k = 0; k < 16; ++k) {
    int u = k * 256 + tid;
    int ci = u >> 6, px = u & 63;
    xtile[px * 65 + ci] = xbase[((size_t)ci << 14) + px];
  }
  __syncthreads();

  const int wv = __builtin_amdgcn_readfirstlane(tid >> 6);
  const int ln = tid & 63;
  float acc[16];
#pragma unroll
  for (int u = 0; u < 16; ++u) acc[u] = bias_c[wv * 16 + u];
  const float* xr = xtile + ln * 65;
#pragma unroll 8
  for (int ci = 0; ci < 64; ++ci) {
    float xv = xr[ci];
    const float* wr = Wc + ci * 64 + wv * 16;
#pragma unroll
    for (int u = 0; u < 16; ++u) acc[u] = fmaf(wr[u], xv, acc[u]);
  }
  float4v* orow = reinterpret_cast<float4v*>(osm) + ln * 17 + wv * 4;
#pragma unroll
  for (int j = 0; j < 4; ++j) {
    float4v t;
#pragma unroll
    for (int s = 0; s < 4; ++s) t[s] = fmaxf(acc[j * 4 + s], 0.f);
    orow[j] = t;
  }
  __syncthreads();

#pragma unroll
  for (int j = 0; j < 2; ++j) {
    int u = j * 256 + tid;
    int px = u >> 3, g = u & 7;
    const float* so = osm + px * 68 + g * 8;
    uint4 vo = make_uint4(pk2(so[0], so[1]), pk2(so[2], so[3]),
                          pk2(so[4], so[5]), pk2(so[6], so[7]));
    *reinterpret_cast<uint4*>(out + (size_t)(p0 + px) * 64 + g * 8) = vo;
    const float* sx = xtile + px * 65 + g * 8;
    uint4 vx = make_uint4(pk2(sx[0], sx[1]), pk2(sx[2], sx[3]),
                          pk2(sx[4], sx[5]), pk2(sx[6], sx[7]));
    *reinterpret_cast<uint4*>(Xb + (size_t)(p0 + px) * 64 + g * 8) = vx;
  }
}

// ---------------------------------------------------------------------------
// encode_apply: FUSED 3x3 MFMA conv + bias + softmax(25) + CARAFE apply.
// One 8x8 low-res tile per block (1024 blocks, 256 threads).
// LDS: [0,25856)   B = wsm fp32 [64 px][101 e-slots]  (stride 101: conflict-
//                  free; overlays A = Wm1t stage [100 pos][72 ci] ushort,
//                  dead after the MFMA loop)
//      [25856,..)  C = xb bf16 [144 pos][72 ch] apply tile (staged phase 1)
// Phases: stage A+C | MFMA | acc->B | softmax in B (256-wide, in-place) |
//         apply (B weights + C taps) -> out.
// ---------------------------------------------------------------------------
__global__ __launch_bounds__(256) void encode_apply(
    const ushort* __restrict__ Wm1t, const ushort* __restrict__ Awt,
    const float* __restrict__ bias2, const ushort* __restrict__ Xb,
    float* __restrict__ out) {
  __shared__ __align__(16) char smem[46592];
  float* wsm = (float*)smem;                    // [64][101] (phase 3+)
  ushort* Xt = (ushort*)smem;                   // [100][72] (phase 1-2)
  ushort* xb = (ushort*)(smem + 25856);         // [144][72]
  const int tid = threadIdx.x;
  const int b = blockIdx.z;
  const int y0 = blockIdx.y * 8, x0 = blockIdx.x * 8;

  // ---- phase 1: stage Wm1t halo tile (A) and Xb apply tile (C) ----
  for (int u = tid; u < 800; u += 256) {        // 100 pos x 8 ci-groups
    int pos = u >> 3, cg = u & 7;
    int iy = pos / 10, ix = pos - iy * 10;
    int gy = y0 + iy - 1, gx = x0 + ix - 1;
    uint4 v = make_uint4(0, 0, 0, 0);
    if ((unsigned)gy < 128u && (unsigned)gx < 128u)
      v = *reinterpret_cast<const uint4*>(
          Wm1t + ((((size_t)b << 14) + (gy << 7) + gx) << 6) + cg * 8);
    *reinterpret_cast<uint4*>(&Xt[pos * 72 + cg * 8]) = v;
  }
  for (int u = tid; u < 1152; u += 256) {       // 144 pos x 8 ch-groups
    int pos = u >> 3, cg = u & 7;
    int iy = pos / 12, ix = pos - iy * 12;
    int gy = y0 + iy - 2, gx = x0 + ix - 2;
    uint4 v = make_uint4(0, 0, 0, 0);
    if ((unsigned)gy < 128u && (unsigned)gx < 128u)
      v = *reinterpret_cast<const uint4*>(
          Xb + (((size_t)b * 16384 + gy * 128 + gx) << 6) + cg * 8);
    *reinterpret_cast<uint4*>(&xb[pos * 72 + cg * 8]) = v;
  }
  __syncthreads();

  // ---- phase 2: implicit-GEMM MFMA K-loop ----
  const int wave = tid >> 6, lane = tid & 63;
  const int q = lane >> 4, px16 = lane & 15;

  float4v acc[2][4];
#pragma unroll
  for (int a = 0; a < 2; ++a)
#pragma unroll
    for (int n = 0; n < 4; ++n) acc[a][n] = (float4v){0.f, 0.f, 0.f, 0.f};

  const short8* Ap = reinterpret_cast<const short8*>(Awt);
#pragma unroll
  for (int kc = 0; kc < 18; ++kc) {
    const int t = kc >> 1, h = kc & 1;
    const int dy = t / 3, dx = t - dy * 3;
    short8 af[2];
#pragma unroll
    for (int a = 0; a < 2; ++a)
      af[a] = Ap[kc * 512 + (wave * 2 + a) * 64 + lane];
    short8 bfr[4];
#pragma unroll
    for (int n = 0; n < 4; ++n) {
      int p = n * 16 + px16;
      int iy = (p >> 3) + dy, ix = (p & 7) + dx;
      bfr[n] = *reinterpret_cast<const short8*>(
          &Xt[(iy * 10 + ix) * 72 + h * 32 + q * 8]);
    }
#pragma unroll
    for (int a = 0; a < 2; ++a)
#pragma unroll
      for (int n = 0; n < 4; ++n)
        acc[a][n] = __builtin_amdgcn_mfma_f32_16x16x32_bf16(
            af[a], bfr[n], acc[a][n], 0, 0, 0);
  }
  __syncthreads();   // A dead; B may now be written

  // ---- phase 3: accumulators -> wsm[px][e] (stride 101, b32 stores) ----
#pragma unroll
  for (int a = 0; a < 2; ++a) {
    int ebase = (wave * 2 + a) * 16 + q * 4;
    if (ebase < 100) {
#pragma unroll
      for (int n = 0; n < 4; ++n) {
        int p = n * 16 + px16;
        float* wp = wsm + p * 101 + ebase;
#pragma unroll
        for (int r = 0; r < 4; ++r) wp[r] = acc[a][n][r];
      }
    }
  }
  __syncthreads();

  // ---- phase 4: 256 parallel softmaxes, in place. t=(px, g=r1*2+r2) ----
  {
    const int px = tid & 63, g = tid >> 6;
    float* wp = wsm + px * 101 + g;
    float v[25];
#pragma unroll
    for (int k = 0; k < 25; ++k) v[k] = wp[4 * k] + bias2[4 * k + g];
    float m = v[0];
#pragma unroll
    for (int k = 1; k < 25; ++k) m = fmaxf(m, v[k]);
    float s = 0.f;
#pragma unroll
    for (int k = 0; k < 25; ++k) {
      v[k] = __expf(v[k] - m);
      s += v[k];
    }
    float inv = 1.f / s;
#pragma unroll
    for (int k = 0; k < 25; ++k) wp[4 * k] = v[k] * inv;
  }
  __syncthreads();

  // ---- phase 5: apply. thread = (px, r1, cq); 32 ch x 2 r2 outputs ----
  {
    const int p = tid & 63, qq = tid >> 6;
    const int r1 = qq & 1, cq = qq >> 1;
    const int py = p >> 3, px = p & 7;
    const float* wrow = wsm + p * 101 + 2 * r1;

    float2 a2[32];
#pragma unroll
    for (int i = 0; i < 32; ++i) a2[i] = make_float2(0.f, 0.f);

#pragma unroll
    for (int k = 0; k < 25; ++k) {
      const int dy = k / 5, dx = k - dy * 5;
      const float w0 = wrow[4 * k];
      const float w1 = wrow[4 * k + 1];
      const ushort* bp = xb + ((py + dy) * 12 + (px + dx)) * 72 + cq * 32;
#pragma unroll
      for (int j = 0; j < 4; ++j) {
        uint4 xv = *reinterpret_cast<const uint4*>(bp + 8 * j);
        const uint xu[4] = {xv.x, xv.y, xv.z, xv.w};
#pragma unroll
        for (int t = 0; t < 4; ++t) {
          float xlo = __uint_as_float(xu[t] << 16);
          float xhi = __uint_as_float(xu[t] & 0xffff0000u);
          int c = j * 8 + t * 2;
          a2[c].x = fmaf(w0, xlo, a2[c].x);
          a2[c].y = fmaf(w1, xlo, a2[c].y);
          a2[c + 1].x = fmaf(w0, xhi, a2[c + 1].x);
          a2[c + 1].y = fmaf(w1, xhi, a2[c + 1].y);
        }
      }
    }

    int yq = (y0 + py) * 2 + r1;
    int xq = (x0 + px) * 2;
#pragma unroll
    for (int ci = 0; ci < 32; ++ci) {
      int c = cq * 32 + ci;
      *reinterpret_cast<float2*>(
          out + ((size_t)(b * 64 + c) * 256 + yq) * 256 + xq) = a2[ci];
    }
  }
}

// ---------------------------------------------------------------------------
extern "C" void kernel_launch(void* const* d_in, const int* in_sizes, int n_in,
                              void* d_out, int out_size, void* d_ws, size_t ws_size,
                              hipStream_t stream) {
  const float* X          = (const float*)d_in[0];
  const float* comp_w     = (const float*)d_in[1];
  const float* comp_gamma = (const float*)d_in[2];
  const float* comp_beta  = (const float*)d_in[3];
  const float* comp_mean  = (const float*)d_in[4];
  const float* comp_var   = (const float*)d_in[5];
  const float* enc_w      = (const float*)d_in[6];
  const float* enc_b      = (const float*)d_in[7];
  const float* enc_gamma  = (const float*)d_in[8];
  const float* enc_beta   = (const float*)d_in[9];
  const float* enc_mean   = (const float*)d_in[10];
  const float* enc_var    = (const float*)d_in[11];
  float* out = (float*)d_out;

  char* ws = (char*)d_ws;
  ushort* Wm1t  = (ushort*)(ws);                    //  8,388,608 B
  ushort* Xb    = (ushort*)(ws + 8388608);          //  8,388,608 B
  ushort* Awt   = (ushort*)(ws + 16777216);         //    147,456 B
  float*  Wc    = (float*)(ws + 16924672);          //     16,384 B
  float*  bias2 = (float*)(ws + 16941056);          //        512 B
  float*  biasc = (float*)(ws + 16941568);          //        256 B

  xform_kernel<<<53, 256, 0, stream>>>(enc_w, enc_gamma, enc_var,
                                       comp_w, comp_gamma, comp_var,
                                       enc_b, enc_beta, enc_mean,
                                       comp_beta, comp_mean,
                                       Awt, Wc, bias2, biasc);
  compress_kernel<<<1024, 256, 0, stream>>>(X, Wc, biasc, Wm1t, Xb);
  encode_apply<<<dim3(16, 16, 4), 256, 0, stream>>>(Wm1t, Awt, bias2, Xb, out);
}